// Round 10
// baseline (1105.920 us; speedup 1.0000x reference)
//
#include <hip/hip_runtime.h>
#include <hip/hip_bf16.h>

typedef __hip_bfloat16 bf16;
typedef __attribute__((ext_vector_type(8))) short bf16x8;
typedef __attribute__((ext_vector_type(4))) float f32x4;

#define NR 65536
#define DIN 1024
#define DH 512
#define DZ 256

__device__ __forceinline__ short f2b(float f) {
    union { __hip_bfloat16 h; short s; } u;
    u.h = __float2bfloat16(f);
    return u.s;
}

__device__ __forceinline__ void gll16(const void* g, void* l) {
    __builtin_amdgcn_global_load_lds(
        (const __attribute__((address_space(1))) char*)g,
        (__attribute__((address_space(3))) char*)l, 16, 0, 0);
}

// ---------------- prep kernels ----------------

__global__ void k_zero(double* __restrict__ p) {
    if (threadIdx.x < 4) p[threadIdx.x] = 0.0;
}

// w[K][N] row-major  ->  wT[N][K] bf16
__global__ void k_wt(const float* __restrict__ w, bf16* __restrict__ wT,
                     int K, int N) {
    int idx = blockIdx.x * 256 + threadIdx.x;
    int n = idx / K, k = idx - n * K;
    wT[idx] = __float2bfloat16(w[(size_t)k * N + n]);
}

// codebook f32 -> bf16 copy + squared norms (one block per codeword, 256 dims)
__global__ void k_cb(const float* __restrict__ cb, bf16* __restrict__ cbb,
                     float* __restrict__ cnorm) {
    int cw = blockIdx.x, d = threadIdx.x;
    float v = cb[(size_t)cw * DZ + d];
    cbb[(size_t)cw * DZ + d] = __float2bfloat16(v);
    float s = v * v;
    #pragma unroll
    for (int m = 1; m < 64; m <<= 1) s += __shfl_xor(s, m, 64);
    __shared__ float red[4];
    if ((d & 63) == 0) red[d >> 6] = s;
    __syncthreads();
    if (d == 0) cnorm[cw] = red[0] + red[1] + red[2] + red[3];
}

// ---------------- GEMM: C = epi(A[M,K] @ BT[N,K]^T + bias) ----------------
// AF32: A operand is f32 in global (converted to bf16 at fragment read)
// EPI 0: bias + exact GELU -> bf16 out
// EPI 1: bias -> f32 out
// EPI 2: bias, d = v - xref, atomic sum(d^2)  (no store)

template <int EPI, int AF32>
__global__ __launch_bounds__(256)
void k_gemm(const void* __restrict__ Ain, const bf16* __restrict__ BT,
            const float* __restrict__ bias, bf16* __restrict__ outb,
            float* __restrict__ outf, const float* __restrict__ xref,
            double* __restrict__ lossAcc, int M, int N, int K) {
    __shared__ __align__(16) char AsBuf[AF32 ? 16384 : 8192];
    __shared__ __align__(16) char BsBuf[8192];
    const int tid = threadIdx.x;
    const int bm = blockIdx.y, bn = blockIdx.x;
    const int w = tid >> 6, l = tid & 63, g = l >> 4, c = l & 15;
    const int wr = w >> 1, wc = w & 1;

    f32x4 acc[4][4] = {};

    const int o1 = tid * 16;
    const int o2 = o1 + 4096;
    const int br1 = o1 >> 6, bcol1 = (o1 & 63) >> 1;
    const int br2 = o2 >> 6, bcol2 = (o2 & 63) >> 1;
    const bf16* Bbase = BT + (size_t)(bn * 128) * K;
    const bf16* Ab = (const bf16*)Ain;
    const float* Af = (const float*)Ain;

    for (int k0 = 0; k0 < K; k0 += 32) {
        __syncthreads();
        if (AF32) {
            #pragma unroll
            for (int j = 0; j < 4; j++) {
                const int ob = o1 + j * 4096;
                const int ar = ob >> 7, ac = (ob & 127) >> 2;
                gll16(Af + (size_t)(bm * 128 + ar) * K + k0 + ac, AsBuf + ob);
            }
        } else {
            gll16(Ab + (size_t)(bm * 128 + br1) * K + k0 + bcol1, AsBuf + o1);
            gll16(Ab + (size_t)(bm * 128 + br2) * K + k0 + bcol2, AsBuf + o2);
        }
        gll16(Bbase + (size_t)br1 * K + k0 + bcol1, BsBuf + o1);
        gll16(Bbase + (size_t)br2 * K + k0 + bcol2, BsBuf + o2);
        __syncthreads();

        bf16x8 af[4], bfr[4];
        #pragma unroll
        for (int m = 0; m < 4; m++) {
            const int row = wr * 64 + m * 16 + c;
            if (AF32) {
                const float* p = (const float*)AsBuf + row * 32 + g * 8;
                f32x4 v0 = *(const f32x4*)p;
                f32x4 v1 = *(const f32x4*)(p + 4);
                bf16x8 t;
                t[0]=f2b(v0[0]); t[1]=f2b(v0[1]); t[2]=f2b(v0[2]); t[3]=f2b(v0[3]);
                t[4]=f2b(v1[0]); t[5]=f2b(v1[1]); t[6]=f2b(v1[2]); t[7]=f2b(v1[3]);
                af[m] = t;
            } else {
                af[m] = *(const bf16x8*)((const bf16*)AsBuf + row * 32 + g * 8);
            }
        }
        #pragma unroll
        for (int n = 0; n < 4; n++)
            bfr[n] = *(const bf16x8*)((const bf16*)BsBuf + (wc * 64 + n * 16 + c) * 32 + g * 8);
        #pragma unroll
        for (int m = 0; m < 4; m++)
            #pragma unroll
            for (int n = 0; n < 4; n++)
                acc[m][n] = __builtin_amdgcn_mfma_f32_16x16x32_bf16(
                    af[m], bfr[n], acc[m][n], 0, 0, 0);
    }

    float msum = 0.f;
    #pragma unroll
    for (int n = 0; n < 4; n++) {
        const int col = bn * 128 + wc * 64 + n * 16 + c;
        const float bv = bias[col];
        #pragma unroll
        for (int m = 0; m < 4; m++) {
            const int row0 = bm * 128 + wr * 64 + m * 16 + g * 4;
            #pragma unroll
            for (int r = 0; r < 4; r++) {
                float v = acc[m][n][r] + bv;
                int row = row0 + r;
                if (EPI == 0) {
                    float ge = 0.5f * v * (1.f + erff(v * 0.70710678118654752f));
                    outb[(size_t)row * N + col] = __float2bfloat16(ge);
                } else if (EPI == 1) {
                    outf[(size_t)row * N + col] = v;
                } else {
                    float d = v - xref[(size_t)row * N + col];
                    msum += d * d;
                }
            }
        }
    }
    if (EPI == 2) {
        #pragma unroll
        for (int m = 1; m < 64; m <<= 1) msum += __shfl_xor(msum, m, 64);
        if (l == 0) atomicAdd(lossAcc, (double)msum);
    }
}

// ---------------- fused residual quantizer ----------------
// grid: NR/64 blocks, 256 threads (4 waves x 16 rows).
// Residual held in registers in MFMA A-fragment layout:
//   lane (g = l>>4, c = l&15) owns row c, dims kk*32 + g*8 + j  (kk 0..7, j 0..7)

__global__ __launch_bounds__(256)
void k_rq(const float* __restrict__ z, const bf16* __restrict__ cbb,
          const float* __restrict__ cnorm,
          const float* __restrict__ cbf0, const float* __restrict__ cbf1,
          const float* __restrict__ cbf2,
          bf16* __restrict__ zqb, double* __restrict__ lossAcc) {
    const int tid = threadIdx.x;
    const int w = tid >> 6, l = tid & 63, g = l >> 4, c = l & 15;
    const int rb = blockIdx.x * 64 + w * 16;
    const size_t rowz = (size_t)(rb + c) * DZ;

    float res[8][8];
    #pragma unroll
    for (int kk = 0; kk < 8; kk++) {
        f32x4 v0 = *(const f32x4*)(z + rowz + kk * 32 + g * 8);
        f32x4 v1 = *(const f32x4*)(z + rowz + kk * 32 + g * 8 + 4);
        res[kk][0] = v0[0]; res[kk][1] = v0[1]; res[kk][2] = v0[2]; res[kk][3] = v0[3];
        res[kk][4] = v1[0]; res[kk][5] = v1[1]; res[kk][6] = v1[2]; res[kk][7] = v1[3];
    }

    const float* cbf[3] = {cbf0, cbf1, cbf2};
    const int Ks[3] = {1024, 512, 256};
    const bf16* cbp = cbb;
    const float* cnp = cnorm;
    float loss[3];

    for (int s = 0; s < 3; s++) {
        bf16x8 af[8];
        #pragma unroll
        for (int kk = 0; kk < 8; kk++) {
            bf16x8 t;
            #pragma unroll
            for (int j = 0; j < 8; j++) t[j] = f2b(res[kk][j]);
            af[kk] = t;
        }
        float minv[4] = {3.4e38f, 3.4e38f, 3.4e38f, 3.4e38f};
        int   mini[4] = {0, 0, 0, 0};
        const int nt = Ks[s] / 16;
        for (int t = 0; t < nt; ++t) {
            const bf16* bp = cbp + ((size_t)(t * 16 + c) * DZ + g * 8);
            bf16x8 bfr[8];
            #pragma unroll
            for (int kk = 0; kk < 8; kk++)
                bfr[kk] = *(const bf16x8*)(bp + kk * 32);
            f32x4 acc = {0.f, 0.f, 0.f, 0.f};
            #pragma unroll
            for (int kk = 0; kk < 8; kk++)
                acc = __builtin_amdgcn_mfma_f32_16x16x32_bf16(af[kk], bfr[kk], acc, 0, 0, 0);
            float cn = cnp[t * 16 + c];
            #pragma unroll
            for (int r = 0; r < 4; r++) {
                float d2 = cn - 2.0f * acc[r];
                if (d2 < minv[r]) { minv[r] = d2; mini[r] = t * 16 + c; }
            }
        }
        #pragma unroll
        for (int m = 1; m < 16; m <<= 1) {
            #pragma unroll
            for (int r = 0; r < 4; r++) {
                float ov = __shfl_xor(minv[r], m, 64);
                int   oi = __shfl_xor(mini[r], m, 64);
                if (ov < minv[r] || (ov == minv[r] && oi < mini[r])) {
                    minv[r] = ov; mini[r] = oi;
                }
            }
        }
        int src = (c >> 2) << 4;
        int i0 = __shfl(mini[0], src, 64);
        int i1 = __shfl(mini[1], src, 64);
        int i2 = __shfl(mini[2], src, 64);
        int i3 = __shfl(mini[3], src, 64);
        int rr = c & 3;
        int myidx = rr == 0 ? i0 : rr == 1 ? i1 : rr == 2 ? i2 : i3;

        const float* qp = cbf[s] + (size_t)myidx * DZ + g * 8;
        float ls = 0.f;
        #pragma unroll
        for (int kk = 0; kk < 8; kk++) {
            f32x4 q0 = *(const f32x4*)(qp + kk * 32);
            f32x4 q1 = *(const f32x4*)(qp + kk * 32 + 4);
            #pragma unroll
            for (int j = 0; j < 4; j++) {
                float d = res[kk][j] - q0[j];
                res[kk][j] = d; ls += d * d;
            }
            #pragma unroll
            for (int j = 0; j < 4; j++) {
                float d = res[kk][4 + j] - q1[j];
                res[kk][4 + j] = d; ls += d * d;
            }
        }
        loss[s] = ls;
        cbp += (size_t)Ks[s] * DZ;
        cnp += Ks[s];
    }

    // zq = z - final residual  -> bf16
    #pragma unroll
    for (int kk = 0; kk < 8; kk++) {
        f32x4 v0 = *(const f32x4*)(z + rowz + kk * 32 + g * 8);
        f32x4 v1 = *(const f32x4*)(z + rowz + kk * 32 + g * 8 + 4);
        bf16x8 o;
        o[0] = f2b(v0[0] - res[kk][0]); o[1] = f2b(v0[1] - res[kk][1]);
        o[2] = f2b(v0[2] - res[kk][2]); o[3] = f2b(v0[3] - res[kk][3]);
        o[4] = f2b(v1[0] - res[kk][4]); o[5] = f2b(v1[1] - res[kk][5]);
        o[6] = f2b(v1[2] - res[kk][6]); o[7] = f2b(v1[3] - res[kk][7]);
        *(bf16x8*)((short*)zqb + rowz + kk * 32 + g * 8) = o;
    }

    #pragma unroll
    for (int s = 0; s < 3; s++) {
        float v = loss[s];
        #pragma unroll
        for (int m = 1; m < 64; m <<= 1) v += __shfl_xor(v, m, 64);
        if (l == 0) atomicAdd(&lossAcc[1 + s], (double)v);
    }
}

// ---------------- final: OUTPUT IS FLOAT32 (4 scalars) ----------------

__global__ void k_fin(const double* __restrict__ la, float* __restrict__ out) {
    int i = threadIdx.x;
    if (i == 0) out[0] = (float)(la[0] / ((double)NR * DIN));
    if (i == 1) out[1] = (float)(1.25 * la[1] / ((double)NR * DZ));
    if (i == 2) out[2] = (float)(1.25 * la[2] / ((double)NR * DZ));
    if (i == 3) out[3] = (float)(1.25 * la[3] / ((double)NR * DZ));
}

// ---------------- launch ----------------

extern "C" void kernel_launch(void* const* d_in, const int* in_sizes, int n_in,
                              void* d_out, int out_size, void* d_ws, size_t ws_size,
                              hipStream_t stream) {
    (void)in_sizes; (void)n_in; (void)out_size; (void)ws_size;
    const float* x   = (const float*)d_in[0];
    const float* ew1 = (const float*)d_in[1];
    const float* eb1 = (const float*)d_in[2];
    const float* ew2 = (const float*)d_in[3];
    const float* eb2 = (const float*)d_in[4];
    const float* dw1 = (const float*)d_in[5];
    const float* db1 = (const float*)d_in[6];
    const float* dw2 = (const float*)d_in[7];
    const float* db2 = (const float*)d_in[8];
    const float* cb0 = (const float*)d_in[9];
    const float* cb1 = (const float*)d_in[10];
    const float* cb2 = (const float*)d_in[11];

    // workspace layout (~138 MB)
    char* ws = (char*)d_ws;
    double* lossAcc = (double*)ws;
    size_t off = 256;
    float* z  = (float*)(ws + off);               // RA (67MB)
    bf16* h2  = (bf16*)(ws + off);                //   alias: h2 after z dead
    off += (size_t)NR * DZ * 4;
    bf16* h1  = (bf16*)(ws + off);                // RB (67MB)
    bf16* zqb = h1;                               //   alias: zqb after h1 dead
    off += (size_t)NR * DH * 2;
    bf16* w1T = (bf16*)(ws + off); off += (size_t)DH * DIN * 2;
    bf16* w2T = (bf16*)(ws + off); off += (size_t)DZ * DH * 2;
    bf16* w3T = (bf16*)(ws + off); off += (size_t)DH * DZ * 2;
    bf16* w4T = (bf16*)(ws + off); off += (size_t)DIN * DH * 2;
    bf16* cbb = (bf16*)(ws + off); off += (size_t)1792 * DZ * 2;
    float* cnorm = (float*)(ws + off); off += 1792 * 4;

    k_zero<<<1, 64, 0, stream>>>(lossAcc);
    k_wt<<<DIN * DH / 256, 256, 0, stream>>>(ew1, w1T, DIN, DH);
    k_wt<<<DH * DZ / 256, 256, 0, stream>>>(ew2, w2T, DH, DZ);
    k_wt<<<DZ * DH / 256, 256, 0, stream>>>(dw1, w3T, DZ, DH);
    k_wt<<<DH * DIN / 256, 256, 0, stream>>>(dw2, w4T, DH, DIN);
    k_cb<<<1024, 256, 0, stream>>>(cb0, cbb, cnorm);
    k_cb<<<512, 256, 0, stream>>>(cb1, cbb + (size_t)1024 * DZ, cnorm + 1024);
    k_cb<<<256, 256, 0, stream>>>(cb2, cbb + (size_t)1536 * DZ, cnorm + 1536);

    // encoder
    k_gemm<0, 1><<<dim3(DH / 128, NR / 128), 256, 0, stream>>>(
        x, w1T, eb1, h1, nullptr, nullptr, nullptr, NR, DH, DIN);
    k_gemm<1, 0><<<dim3(DZ / 128, NR / 128), 256, 0, stream>>>(
        h1, w2T, eb2, nullptr, z, nullptr, nullptr, NR, DZ, DH);

    // residual quantizer
    k_rq<<<NR / 64, 256, 0, stream>>>(z, cbb, cnorm, cb0, cb1, cb2, zqb, lossAcc);

    // decoder
    k_gemm<0, 0><<<dim3(DH / 128, NR / 128), 256, 0, stream>>>(
        zqb, w3T, db1, h2, nullptr, nullptr, nullptr, NR, DH, DZ);
    k_gemm<2, 0><<<dim3(DIN / 128, NR / 128), 256, 0, stream>>>(
        h2, w4T, db2, nullptr, nullptr, x, lossAcc, NR, DIN, DH);

    k_fin<<<1, 64, 0, stream>>>(lossAcc, (float*)d_out);
}

// Round 11
// 880.046 us; speedup vs baseline: 1.2567x; 1.2567x over previous
//
#include <hip/hip_runtime.h>
#include <hip/hip_bf16.h>

typedef __hip_bfloat16 bf16;
typedef __attribute__((ext_vector_type(8))) short bf16x8;
typedef __attribute__((ext_vector_type(4))) float f32x4;

#define NR 65536
#define DIN 1024
#define DH 512
#define DZ 256
#define NTILES 112   // 64 + 32 + 16 codeword tiles of 16

__device__ __forceinline__ short f2b(float f) {
    union { __hip_bfloat16 h; short s; } u;
    u.h = __float2bfloat16(f);
    return u.s;
}
__device__ __forceinline__ float b2f(short s) {
    union { short s; __hip_bfloat16 h; } u;
    u.s = s;
    return __bfloat162float(u.h);
}

__device__ __forceinline__ void gll16(const void* g, void* l) {
    __builtin_amdgcn_global_load_lds(
        (const __attribute__((address_space(1))) char*)g,
        (__attribute__((address_space(3))) char*)l, 16, 0, 0);
}

// ---------------- prep kernels ----------------

__global__ void k_zero(double* __restrict__ p) {
    if (threadIdx.x < 4) p[threadIdx.x] = 0.0;
}

// w[K][N] row-major  ->  wT[N][K] bf16
__global__ void k_wt(const float* __restrict__ w, bf16* __restrict__ wT,
                     int K, int N) {
    int idx = blockIdx.x * 256 + threadIdx.x;
    int n = idx / K, k = idx - n * K;
    wT[idx] = __float2bfloat16(w[(size_t)k * N + n]);
}

// codebook f32 -> bf16 SWIZZLED copy + squared norms.
// Swizzle: cbb[cw][e] = cb[cw][e ^ ((cw&7)<<3)]  (16B-block XOR within row,
// matches LDS read-side swizzle in k_rq; breaks the 16-way bank conflict).
__global__ void k_cb(const float* __restrict__ cb, bf16* __restrict__ cbb,
                     float* __restrict__ cnorm) {
    int cw = blockIdx.x, d = threadIdx.x;
    int dsrc = d ^ ((cw & 7) << 3);
    float v = cb[(size_t)cw * DZ + dsrc];
    cbb[(size_t)cw * DZ + d] = __float2bfloat16(v);
    float s = v * v;   // sums over all elements regardless of permutation
    #pragma unroll
    for (int m = 1; m < 64; m <<= 1) s += __shfl_xor(s, m, 64);
    __shared__ float red[4];
    if ((d & 63) == 0) red[d >> 6] = s;
    __syncthreads();
    if (d == 0) cnorm[cw] = red[0] + red[1] + red[2] + red[3];
}

// ---------------- GEMM: C = epi(A[M,K] @ BT[N,K]^T + bias) ----------------
// (unchanged from round 10 — validated)

template <int EPI, int AF32>
__global__ __launch_bounds__(256)
void k_gemm(const void* __restrict__ Ain, const bf16* __restrict__ BT,
            const float* __restrict__ bias, bf16* __restrict__ outb,
            float* __restrict__ outf, const float* __restrict__ xref,
            double* __restrict__ lossAcc, int M, int N, int K) {
    __shared__ __align__(16) char AsBuf[AF32 ? 16384 : 8192];
    __shared__ __align__(16) char BsBuf[8192];
    const int tid = threadIdx.x;
    const int bm = blockIdx.y, bn = blockIdx.x;
    const int w = tid >> 6, l = tid & 63, g = l >> 4, c = l & 15;
    const int wr = w >> 1, wc = w & 1;

    f32x4 acc[4][4] = {};

    const int o1 = tid * 16;
    const int o2 = o1 + 4096;
    const int br1 = o1 >> 6, bcol1 = (o1 & 63) >> 1;
    const int br2 = o2 >> 6, bcol2 = (o2 & 63) >> 1;
    const bf16* Bbase = BT + (size_t)(bn * 128) * K;
    const bf16* Ab = (const bf16*)Ain;
    const float* Af = (const float*)Ain;

    for (int k0 = 0; k0 < K; k0 += 32) {
        __syncthreads();
        if (AF32) {
            #pragma unroll
            for (int j = 0; j < 4; j++) {
                const int ob = o1 + j * 4096;
                const int ar = ob >> 7, ac = (ob & 127) >> 2;
                gll16(Af + (size_t)(bm * 128 + ar) * K + k0 + ac, AsBuf + ob);
            }
        } else {
            gll16(Ab + (size_t)(bm * 128 + br1) * K + k0 + bcol1, AsBuf + o1);
            gll16(Ab + (size_t)(bm * 128 + br2) * K + k0 + bcol2, AsBuf + o2);
        }
        gll16(Bbase + (size_t)br1 * K + k0 + bcol1, BsBuf + o1);
        gll16(Bbase + (size_t)br2 * K + k0 + bcol2, BsBuf + o2);
        __syncthreads();

        bf16x8 af[4], bfr[4];
        #pragma unroll
        for (int m = 0; m < 4; m++) {
            const int row = wr * 64 + m * 16 + c;
            if (AF32) {
                const float* p = (const float*)AsBuf + row * 32 + g * 8;
                f32x4 v0 = *(const f32x4*)p;
                f32x4 v1 = *(const f32x4*)(p + 4);
                bf16x8 t;
                t[0]=f2b(v0[0]); t[1]=f2b(v0[1]); t[2]=f2b(v0[2]); t[3]=f2b(v0[3]);
                t[4]=f2b(v1[0]); t[5]=f2b(v1[1]); t[6]=f2b(v1[2]); t[7]=f2b(v1[3]);
                af[m] = t;
            } else {
                af[m] = *(const bf16x8*)((const bf16*)AsBuf + row * 32 + g * 8);
            }
        }
        #pragma unroll
        for (int n = 0; n < 4; n++)
            bfr[n] = *(const bf16x8*)((const bf16*)BsBuf + (wc * 64 + n * 16 + c) * 32 + g * 8);
        #pragma unroll
        for (int m = 0; m < 4; m++)
            #pragma unroll
            for (int n = 0; n < 4; n++)
                acc[m][n] = __builtin_amdgcn_mfma_f32_16x16x32_bf16(
                    af[m], bfr[n], acc[m][n], 0, 0, 0);
    }

    float msum = 0.f;
    #pragma unroll
    for (int n = 0; n < 4; n++) {
        const int col = bn * 128 + wc * 64 + n * 16 + c;
        const float bv = bias[col];
        #pragma unroll
        for (int m = 0; m < 4; m++) {
            const int row0 = bm * 128 + wr * 64 + m * 16 + g * 4;
            #pragma unroll
            for (int r = 0; r < 4; r++) {
                float v = acc[m][n][r] + bv;
                int row = row0 + r;
                if (EPI == 0) {
                    float ge = 0.5f * v * (1.f + erff(v * 0.70710678118654752f));
                    outb[(size_t)row * N + col] = __float2bfloat16(ge);
                } else if (EPI == 1) {
                    outf[(size_t)row * N + col] = v;
                } else {
                    float d = v - xref[(size_t)row * N + col];
                    msum += d * d;
                }
            }
        }
    }
    if (EPI == 2) {
        #pragma unroll
        for (int m = 1; m < 64; m <<= 1) msum += __shfl_xor(msum, m, 64);
        if (l == 0) atomicAdd(lossAcc, (double)msum);
    }
}

// ---------------- fused residual quantizer v2 ----------------
// 4 waves x 16 rows; codebook tiles (16 codewords = 8KB) double-buffered in
// LDS via global_load_lds; XOR-swizzled layout -> conflict-free ds_read_b128.
// Residual kept as bf16 MFMA A-fragments (saves 64 VGPRs; <=128 total).

__global__ __launch_bounds__(256, 4)
void k_rq(const float* __restrict__ z, const bf16* __restrict__ cbb,
          const float* __restrict__ cnorm,
          const float* __restrict__ cbf0, const float* __restrict__ cbf1,
          const float* __restrict__ cbf2,
          bf16* __restrict__ zqb, double* __restrict__ lossAcc) {
    __shared__ __align__(16) char tileB[2][8192];
    __shared__ float cn_lds[1792];
    const int tid = threadIdx.x;
    const int w = tid >> 6, l = tid & 63, g = l >> 4, c = l & 15;
    const int rb = blockIdx.x * 64 + w * 16;
    const size_t rowz = (size_t)(rb + c) * DZ;

    for (int i = tid; i < 1792; i += 256) cn_lds[i] = cnorm[i];

    // initial residual = bf16(z) packed directly into A fragments
    bf16x8 af[8];
    #pragma unroll
    for (int kk = 0; kk < 8; kk++) {
        f32x4 v0 = *(const f32x4*)(z + rowz + kk * 32 + g * 8);
        f32x4 v1 = *(const f32x4*)(z + rowz + kk * 32 + g * 8 + 4);
        bf16x8 t;
        t[0]=f2b(v0[0]); t[1]=f2b(v0[1]); t[2]=f2b(v0[2]); t[3]=f2b(v0[3]);
        t[4]=f2b(v1[0]); t[5]=f2b(v1[1]); t[6]=f2b(v1[2]); t[7]=f2b(v1[3]);
        af[kk] = t;
    }

    // swizzled LDS read base: row c (512B); byte within row for (g,kk):
    //   ((kk*64 + g*16) ^ ((c&7)<<4))  ==  (P ^ (kk<<6)) - c*512
    const int c0 = c & 7;
    const int P = c * 512 + ((g * 16) ^ ((c0 & 3) << 4)) + ((c0 >> 2) << 6);

    const char* cbbase = (const char*)cbb;

    STAGE_DEF:;
    auto STAGE = [&](int b, int gt) {
        const char* src = cbbase + (size_t)gt * 8192 + tid * 16;
        gll16(src, tileB[b] + tid * 16);
        gll16(src + 4096, tileB[b] + tid * 16 + 4096);
    };

    STAGE(0, 0);
    __syncthreads();   // drains vmcnt: tile 0 staged; cn_lds visible

    const float* cbf[3] = {cbf0, cbf1, cbf2};
    const int Ks[3] = {1024, 512, 256};
    int cur = 0, gt = 0, cnbase = 0;
    float loss[3];

    for (int s = 0; s < 3; s++) {
        const int nt = Ks[s] >> 4;
        float minv[4] = {3.4e38f, 3.4e38f, 3.4e38f, 3.4e38f};
        int   mini[4] = {0, 0, 0, 0};
        for (int t = 0; t < nt; ++t, ++gt) {
            if (gt + 1 < NTILES) STAGE(cur ^ 1, gt + 1);   // prefetch next tile
            const char* tp = tileB[cur];
            bf16x8 bfr[8];
            #pragma unroll
            for (int kk = 0; kk < 8; kk++)
                bfr[kk] = *(const bf16x8*)(tp + (P ^ (kk << 6)));
            f32x4 acc = {0.f, 0.f, 0.f, 0.f};
            #pragma unroll
            for (int kk = 0; kk < 8; kk++)
                acc = __builtin_amdgcn_mfma_f32_16x16x32_bf16(af[kk], bfr[kk], acc, 0, 0, 0);
            float cn = cn_lds[cnbase + t * 16 + c];
            #pragma unroll
            for (int r = 0; r < 4; r++) {
                float d2 = cn - 2.0f * acc[r];
                if (d2 < minv[r]) { minv[r] = d2; mini[r] = t * 16 + c; }
            }
            __syncthreads();   // next tile staged; all waves done with cur
            cur ^= 1;
        }
        // reduce (min, idx) across the 16 col-lanes of each group
        #pragma unroll
        for (int m = 1; m < 16; m <<= 1) {
            #pragma unroll
            for (int r = 0; r < 4; r++) {
                float ov = __shfl_xor(minv[r], m, 64);
                int   oi = __shfl_xor(mini[r], m, 64);
                if (ov < minv[r] || (ov == minv[r] && oi < mini[r])) {
                    minv[r] = ov; mini[r] = oi;
                }
            }
        }
        // redistribute: lane needs idx of row==c (held in group c>>2, reg c&3)
        int src = (c >> 2) << 4;
        int i0 = __shfl(mini[0], src, 64);
        int i1 = __shfl(mini[1], src, 64);
        int i2 = __shfl(mini[2], src, 64);
        int i3 = __shfl(mini[3], src, 64);
        int rr = c & 3;
        int myidx = rr == 0 ? i0 : rr == 1 ? i1 : rr == 2 ? i2 : i3;

        // gather q (f32 codebook), update residual fragments, loss
        const float* qp = cbf[s] + (size_t)myidx * DZ + g * 8;
        float ls = 0.f;
        #pragma unroll
        for (int kk = 0; kk < 8; kk++) {
            f32x4 q0 = *(const f32x4*)(qp + kk * 32);
            f32x4 q1 = *(const f32x4*)(qp + kk * 32 + 4);
            bf16x8 a = af[kk];
            bf16x8 t;
            #pragma unroll
            for (int j = 0; j < 4; j++) {
                float d = b2f(a[j]) - q0[j];
                ls += d * d;
                t[j] = f2b(d);
            }
            #pragma unroll
            for (int j = 0; j < 4; j++) {
                float d = b2f(a[4 + j]) - q1[j];
                ls += d * d;
                t[4 + j] = f2b(d);
            }
            af[kk] = t;
        }
        loss[s] = ls;
        cnbase += Ks[s];
    }

    // zq = z - res_final  -> bf16
    #pragma unroll
    for (int kk = 0; kk < 8; kk++) {
        f32x4 v0 = *(const f32x4*)(z + rowz + kk * 32 + g * 8);
        f32x4 v1 = *(const f32x4*)(z + rowz + kk * 32 + g * 8 + 4);
        bf16x8 a = af[kk];
        bf16x8 o;
        o[0] = f2b(v0[0] - b2f(a[0])); o[1] = f2b(v0[1] - b2f(a[1]));
        o[2] = f2b(v0[2] - b2f(a[2])); o[3] = f2b(v0[3] - b2f(a[3]));
        o[4] = f2b(v1[0] - b2f(a[4])); o[5] = f2b(v1[1] - b2f(a[5]));
        o[6] = f2b(v1[2] - b2f(a[6])); o[7] = f2b(v1[3] - b2f(a[7]));
        *(bf16x8*)((short*)zqb + rowz + kk * 32 + g * 8) = o;
    }

    #pragma unroll
    for (int s = 0; s < 3; s++) {
        float v = loss[s];
        #pragma unroll
        for (int m = 1; m < 64; m <<= 1) v += __shfl_xor(v, m, 64);
        if (l == 0) atomicAdd(&lossAcc[1 + s], (double)v);
    }
}

// ---------------- final: output float32 (4 scalars) ----------------

__global__ void k_fin(const double* __restrict__ la, float* __restrict__ out) {
    int i = threadIdx.x;
    if (i == 0) out[0] = (float)(la[0] / ((double)NR * DIN));
    if (i == 1) out[1] = (float)(1.25 * la[1] / ((double)NR * DZ));
    if (i == 2) out[2] = (float)(1.25 * la[2] / ((double)NR * DZ));
    if (i == 3) out[3] = (float)(1.25 * la[3] / ((double)NR * DZ));
}

// ---------------- launch ----------------

extern "C" void kernel_launch(void* const* d_in, const int* in_sizes, int n_in,
                              void* d_out, int out_size, void* d_ws, size_t ws_size,
                              hipStream_t stream) {
    (void)in_sizes; (void)n_in; (void)out_size; (void)ws_size;
    const float* x   = (const float*)d_in[0];
    const float* ew1 = (const float*)d_in[1];
    const float* eb1 = (const float*)d_in[2];
    const float* ew2 = (const float*)d_in[3];
    const float* eb2 = (const float*)d_in[4];
    const float* dw1 = (const float*)d_in[5];
    const float* db1 = (const float*)d_in[6];
    const float* dw2 = (const float*)d_in[7];
    const float* db2 = (const float*)d_in[8];
    const float* cb0 = (const float*)d_in[9];
    const float* cb1 = (const float*)d_in[10];
    const float* cb2 = (const float*)d_in[11];

    // workspace layout (~138 MB)
    char* ws = (char*)d_ws;
    double* lossAcc = (double*)ws;
    size_t off = 256;
    float* z  = (float*)(ws + off);               // RA (67MB)
    bf16* h2  = (bf16*)(ws + off);                //   alias: h2 after z dead
    off += (size_t)NR * DZ * 4;
    bf16* h1  = (bf16*)(ws + off);                // RB (67MB)
    bf16* zqb = h1;                               //   alias: zqb after h1 dead
    off += (size_t)NR * DH * 2;
    bf16* w1T = (bf16*)(ws + off); off += (size_t)DH * DIN * 2;
    bf16* w2T = (bf16*)(ws + off); off += (size_t)DZ * DH * 2;
    bf16* w3T = (bf16*)(ws + off); off += (size_t)DH * DZ * 2;
    bf16* w4T = (bf16*)(ws + off); off += (size_t)DIN * DH * 2;
    bf16* cbb = (bf16*)(ws + off); off += (size_t)1792 * DZ * 2;
    float* cnorm = (float*)(ws + off); off += 1792 * 4;

    k_zero<<<1, 64, 0, stream>>>(lossAcc);
    k_wt<<<DIN * DH / 256, 256, 0, stream>>>(ew1, w1T, DIN, DH);
    k_wt<<<DH * DZ / 256, 256, 0, stream>>>(ew2, w2T, DH, DZ);
    k_wt<<<DZ * DH / 256, 256, 0, stream>>>(dw1, w3T, DZ, DH);
    k_wt<<<DH * DIN / 256, 256, 0, stream>>>(dw2, w4T, DH, DIN);
    k_cb<<<1024, 256, 0, stream>>>(cb0, cbb, cnorm);
    k_cb<<<512, 256, 0, stream>>>(cb1, cbb + (size_t)1024 * DZ, cnorm + 1024);
    k_cb<<<256, 256, 0, stream>>>(cb2, cbb + (size_t)1536 * DZ, cnorm + 1536);

    // encoder
    k_gemm<0, 1><<<dim3(DH / 128, NR / 128), 256, 0, stream>>>(
        x, w1T, eb1, h1, nullptr, nullptr, nullptr, NR, DH, DIN);
    k_gemm<1, 0><<<dim3(DZ / 128, NR / 128), 256, 0, stream>>>(
        h1, w2T, eb2, nullptr, z, nullptr, nullptr, NR, DZ, DH);

    // residual quantizer (LDS-staged codebook, double-buffered)
    k_rq<<<NR / 64, 256, 0, stream>>>(z, cbb, cnorm, cb0, cb1, cb2, zqb, lossAcc);

    // decoder
    k_gemm<0, 0><<<dim3(DH / 128, NR / 128), 256, 0, stream>>>(
        zqb, w3T, db1, h2, nullptr, nullptr, nullptr, NR, DH, DZ);
    k_gemm<2, 0><<<dim3(DIN / 128, NR / 128), 256, 0, stream>>>(
        h2, w4T, db2, nullptr, nullptr, x, lossAcc, NR, DIN, DH);

    k_fin<<<1, 64, 0, stream>>>(lossAcc, (float*)d_out);
}

// Round 12
// 700.574 us; speedup vs baseline: 1.5786x; 1.2562x over previous
//
#include <hip/hip_runtime.h>
#include <hip/hip_bf16.h>

typedef __hip_bfloat16 bf16;
typedef __attribute__((ext_vector_type(8))) short bf16x8;
typedef __attribute__((ext_vector_type(4))) float f32x4;

#define NR 65536
#define DIN 1024
#define DH 512
#define DZ 256

__device__ __forceinline__ short f2b(float f) {
    union { __hip_bfloat16 h; short s; } u;
    u.h = __float2bfloat16(f);
    return u.s;
}
__device__ __forceinline__ float b2f(short s) {
    union { short s; __hip_bfloat16 h; } u;
    u.s = s;
    return __bfloat162float(u.h);
}

__device__ __forceinline__ void gll16(const void* g, void* l) {
    __builtin_amdgcn_global_load_lds(
        (const __attribute__((address_space(1))) char*)g,
        (__attribute__((address_space(3))) char*)l, 16, 0, 0);
}

// ---------------- prep kernels ----------------

__global__ void k_zero(double* __restrict__ p) {
    if (threadIdx.x < 4) p[threadIdx.x] = 0.0;
}

// tiled transpose: w[K][N] f32 -> wT[N][K] bf16 (64x64 LDS tiles, coalesced both sides)
__global__ __launch_bounds__(256)
void k_wt(const float* __restrict__ w, bf16* __restrict__ wT, int K, int N) {
    __shared__ float t[64][65];
    const int k0 = blockIdx.x * 64, n0 = blockIdx.y * 64;
    const int tx = threadIdx.x & 63, ty = threadIdx.x >> 6;
    #pragma unroll
    for (int i = 0; i < 16; i++) {
        int r = ty + i * 4;
        t[r][tx] = w[(size_t)(k0 + r) * N + n0 + tx];
    }
    __syncthreads();
    #pragma unroll
    for (int i = 0; i < 16; i++) {
        int r = ty + i * 4;
        wT[(size_t)(n0 + r) * K + k0 + tx] = __float2bfloat16(t[tx][r]);
    }
}

// codebook f32 -> bf16 SWIZZLED copy + squared norms (swizzle matches k_rq reads)
__global__ void k_cb(const float* __restrict__ cb, bf16* __restrict__ cbb,
                     float* __restrict__ cnorm) {
    int cw = blockIdx.x, d = threadIdx.x;
    int dsrc = d ^ ((cw & 7) << 3);
    float v = cb[(size_t)cw * DZ + dsrc];
    cbb[(size_t)cw * DZ + d] = __float2bfloat16(v);
    float s = v * v;
    #pragma unroll
    for (int m = 1; m < 64; m <<= 1) s += __shfl_xor(s, m, 64);
    __shared__ float red[4];
    if ((d & 63) == 0) red[d >> 6] = s;
    __syncthreads();
    if (d == 0) cnorm[cw] = red[0] + red[1] + red[2] + red[3];
}

// ---------------- GEMM: C = epi(A[M,K] @ BT[N,K]^T + bias) ----------------
// 1-D grid, XCD-chunked swizzle: same-bm blocks (sharing the A panel) land on
// the same XCD consecutively -> A panel L2-hits instead of HBM refetch.
// EPI 0: bias + exact GELU -> bf16 | EPI 1: bias -> bf16 | EPI 2: MSE vs xref

template <int EPI, int AF32, int LOGG>
__global__ __launch_bounds__(256)
void k_gemm(const void* __restrict__ Ain, const bf16* __restrict__ BT,
            const float* __restrict__ bias, bf16* __restrict__ outb,
            const float* __restrict__ xref, double* __restrict__ lossAcc,
            int M, int N, int K) {
    __shared__ __align__(16) char AsBuf[AF32 ? 16384 : 8192];
    __shared__ __align__(16) char BsBuf[8192];
    const int tid = threadIdx.x;
    const int bid = blockIdx.x;
    const int tt = bid >> 3;
    const int bn = tt & ((1 << LOGG) - 1);
    const int bm = (bid & 7) + ((tt >> LOGG) << 3);
    const int w = tid >> 6, l = tid & 63, g = l >> 4, c = l & 15;
    const int wr = w >> 1, wc = w & 1;

    f32x4 acc[4][4] = {};

    const int o1 = tid * 16;
    const int o2 = o1 + 4096;
    const int br1 = o1 >> 6, bcol1 = (o1 & 63) >> 1;
    const int br2 = o2 >> 6, bcol2 = (o2 & 63) >> 1;
    const bf16* Bbase = BT + (size_t)(bn * 128) * K;
    const bf16* Ab = (const bf16*)Ain;
    const float* Af = (const float*)Ain;

    for (int k0 = 0; k0 < K; k0 += 32) {
        __syncthreads();
        if (AF32) {
            #pragma unroll
            for (int j = 0; j < 4; j++) {
                const int ob = o1 + j * 4096;
                const int ar = ob >> 7, ac = (ob & 127) >> 2;
                gll16(Af + (size_t)(bm * 128 + ar) * K + k0 + ac, AsBuf + ob);
            }
        } else {
            gll16(Ab + (size_t)(bm * 128 + br1) * K + k0 + bcol1, AsBuf + o1);
            gll16(Ab + (size_t)(bm * 128 + br2) * K + k0 + bcol2, AsBuf + o2);
        }
        gll16(Bbase + (size_t)br1 * K + k0 + bcol1, BsBuf + o1);
        gll16(Bbase + (size_t)br2 * K + k0 + bcol2, BsBuf + o2);
        __syncthreads();

        bf16x8 af[4], bfr[4];
        #pragma unroll
        for (int m = 0; m < 4; m++) {
            const int row = wr * 64 + m * 16 + c;
            if (AF32) {
                const float* p = (const float*)AsBuf + row * 32 + g * 8;
                f32x4 v0 = *(const f32x4*)p;
                f32x4 v1 = *(const f32x4*)(p + 4);
                bf16x8 t;
                t[0]=f2b(v0[0]); t[1]=f2b(v0[1]); t[2]=f2b(v0[2]); t[3]=f2b(v0[3]);
                t[4]=f2b(v1[0]); t[5]=f2b(v1[1]); t[6]=f2b(v1[2]); t[7]=f2b(v1[3]);
                af[m] = t;
            } else {
                af[m] = *(const bf16x8*)((const bf16*)AsBuf + row * 32 + g * 8);
            }
        }
        #pragma unroll
        for (int n = 0; n < 4; n++)
            bfr[n] = *(const bf16x8*)((const bf16*)BsBuf + (wc * 64 + n * 16 + c) * 32 + g * 8);
        #pragma unroll
        for (int m = 0; m < 4; m++)
            #pragma unroll
            for (int n = 0; n < 4; n++)
                acc[m][n] = __builtin_amdgcn_mfma_f32_16x16x32_bf16(
                    af[m], bfr[n], acc[m][n], 0, 0, 0);
    }

    float msum = 0.f;
    #pragma unroll
    for (int n = 0; n < 4; n++) {
        const int col = bn * 128 + wc * 64 + n * 16 + c;
        const float bv = bias[col];
        #pragma unroll
        for (int m = 0; m < 4; m++) {
            const int row0 = bm * 128 + wr * 64 + m * 16 + g * 4;
            #pragma unroll
            for (int r = 0; r < 4; r++) {
                float v = acc[m][n][r] + bv;
                int row = row0 + r;
                if (EPI == 0) {
                    float ge = 0.5f * v * (1.f + erff(v * 0.70710678118654752f));
                    outb[(size_t)row * N + col] = __float2bfloat16(ge);
                } else if (EPI == 1) {
                    outb[(size_t)row * N + col] = __float2bfloat16(v);
                } else {
                    float d = v - xref[(size_t)row * N + col];
                    msum += d * d;
                }
            }
        }
    }
    if (EPI == 2) {
        #pragma unroll
        for (int m = 1; m < 64; m <<= 1) msum += __shfl_xor(msum, m, 64);
        if (l == 0) atomicAdd(lossAcc, (double)msum);
    }
}

// ---------------- fused residual quantizer v3 ----------------
// 512 blocks x 256 thr (4 waves); wave owns 32 rows (2 A-fragment sets that
// SHARE every codebook LDS read). Codebook staged in 128-codeword mega-tiles
// (64KB LDS, single buffer, 2 barriers per mega-tile = 28 total).
// No launch-bounds min-waves: VGPR cap 256 -> no scratch spill.

__global__ __launch_bounds__(256)
void k_rq(const bf16* __restrict__ z, const bf16* __restrict__ cbb,
          const float* __restrict__ cnorm,
          const float* __restrict__ cbf0, const float* __restrict__ cbf1,
          const float* __restrict__ cbf2,
          bf16* __restrict__ zqb, double* __restrict__ lossAcc) {
    __shared__ __align__(16) char mt[65536];
    __shared__ float cn_lds[1792];
    const int tid = threadIdx.x;
    const int w = tid >> 6, l = tid & 63, g = l >> 4, c = l & 15;
    const int rowbase = blockIdx.x * 128 + w * 32;

    for (int i = tid; i < 1792; i += 256) cn_lds[i] = cnorm[i];

    // residual fragments: set m covers rows rowbase + m*16 + c
    bf16x8 af[2][8];
    #pragma unroll
    for (int m = 0; m < 2; m++) {
        const short* zp = (const short*)z + (size_t)(rowbase + m * 16 + c) * DZ + g * 8;
        #pragma unroll
        for (int kk = 0; kk < 8; kk++)
            af[m][kk] = *(const bf16x8*)(zp + kk * 32);
    }

    const int c0 = c & 7;
    const int Pbase = c * 512 + ((g * 16) ^ ((c0 & 3) << 4)) + ((c0 >> 2) << 6);

    const float* cbf[3] = {cbf0, cbf1, cbf2};
    const int Ks[3] = {1024, 512, 256};
    int mtg = 0, cnbase = 0;
    float lsum[3];

    for (int s = 0; s < 3; s++) {
        const int nmt = Ks[s] >> 7;   // 8, 4, 2 mega-tiles
        float minv[2][4] = {{3.4e38f, 3.4e38f, 3.4e38f, 3.4e38f},
                            {3.4e38f, 3.4e38f, 3.4e38f, 3.4e38f}};
        int mini[2][4] = {};
        for (int imt = 0; imt < nmt; imt++, mtg++) {
            __syncthreads();   // previous mega-tile fully consumed by all waves
            const char* src = (const char*)cbb + (size_t)mtg * 65536 + tid * 16;
            #pragma unroll
            for (int st = 0; st < 16; st++)
                gll16(src + (size_t)st * 4096, mt + st * 4096 + tid * 16);
            __syncthreads();   // staged (compiler drains vmcnt before barrier)
            #pragma unroll
            for (int sub = 0; sub < 8; sub++) {
                const char* tp = mt + sub * 8192;
                bf16x8 bfr[8];
                #pragma unroll
                for (int kk = 0; kk < 8; kk++)
                    bfr[kk] = *(const bf16x8*)(tp + (Pbase ^ (kk << 6)));
                f32x4 a0 = {0.f, 0.f, 0.f, 0.f}, a1 = {0.f, 0.f, 0.f, 0.f};
                #pragma unroll
                for (int kk = 0; kk < 8; kk++) {
                    a0 = __builtin_amdgcn_mfma_f32_16x16x32_bf16(af[0][kk], bfr[kk], a0, 0, 0, 0);
                    a1 = __builtin_amdgcn_mfma_f32_16x16x32_bf16(af[1][kk], bfr[kk], a1, 0, 0, 0);
                }
                const int cw = imt * 128 + sub * 16 + c;
                const float cn = cn_lds[cnbase + cw];
                #pragma unroll
                for (int r = 0; r < 4; r++) {
                    float d0 = cn - 2.0f * a0[r];
                    if (d0 < minv[0][r]) { minv[0][r] = d0; mini[0][r] = cw; }
                    float d1 = cn - 2.0f * a1[r];
                    if (d1 < minv[1][r]) { minv[1][r] = d1; mini[1][r] = cw; }
                }
            }
        }
        float ls = 0.f;
        #pragma unroll
        for (int m = 0; m < 2; m++) {
            #pragma unroll
            for (int mm = 1; mm < 16; mm <<= 1) {
                #pragma unroll
                for (int r = 0; r < 4; r++) {
                    float ov = __shfl_xor(minv[m][r], mm, 64);
                    int   oi = __shfl_xor(mini[m][r], mm, 64);
                    if (ov < minv[m][r] || (ov == minv[m][r] && oi < mini[m][r])) {
                        minv[m][r] = ov; mini[m][r] = oi;
                    }
                }
            }
            int srcl = (c >> 2) << 4;
            int i0 = __shfl(mini[m][0], srcl, 64);
            int i1 = __shfl(mini[m][1], srcl, 64);
            int i2 = __shfl(mini[m][2], srcl, 64);
            int i3 = __shfl(mini[m][3], srcl, 64);
            int rr = c & 3;
            int myidx = rr == 0 ? i0 : rr == 1 ? i1 : rr == 2 ? i2 : i3;

            const float* qp = cbf[s] + (size_t)myidx * DZ + g * 8;
            #pragma unroll
            for (int kk = 0; kk < 8; kk++) {
                f32x4 q0 = *(const f32x4*)(qp + kk * 32);
                f32x4 q1 = *(const f32x4*)(qp + kk * 32 + 4);
                bf16x8 a = af[m][kk];
                bf16x8 t;
                #pragma unroll
                for (int j = 0; j < 4; j++) {
                    float d = b2f(a[j]) - q0[j];
                    ls += d * d; t[j] = f2b(d);
                }
                #pragma unroll
                for (int j = 0; j < 4; j++) {
                    float d = b2f(a[4 + j]) - q1[j];
                    ls += d * d; t[4 + j] = f2b(d);
                }
                af[m][kk] = t;
            }
        }
        lsum[s] = ls;
        cnbase += Ks[s];
    }

    // zq = z - res_final  -> bf16
    #pragma unroll
    for (int m = 0; m < 2; m++) {
        const short* zp = (const short*)z + (size_t)(rowbase + m * 16 + c) * DZ + g * 8;
        short* op = (short*)zqb + (size_t)(rowbase + m * 16 + c) * DZ + g * 8;
        #pragma unroll
        for (int kk = 0; kk < 8; kk++) {
            bf16x8 zv = *(const bf16x8*)(zp + kk * 32);
            bf16x8 a = af[m][kk];
            bf16x8 o;
            #pragma unroll
            for (int j = 0; j < 8; j++)
                o[j] = f2b(b2f(zv[j]) - b2f(a[j]));
            *(bf16x8*)(op + kk * 32) = o;
        }
    }

    #pragma unroll
    for (int s = 0; s < 3; s++) {
        float v = lsum[s];
        #pragma unroll
        for (int mm = 1; mm < 64; mm <<= 1) v += __shfl_xor(v, mm, 64);
        if (l == 0) atomicAdd(&lossAcc[1 + s], (double)v);
    }
}

// ---------------- final: output float32 (4 scalars) ----------------

__global__ void k_fin(const double* __restrict__ la, float* __restrict__ out) {
    int i = threadIdx.x;
    if (i == 0) out[0] = (float)(la[0] / ((double)NR * DIN));
    if (i == 1) out[1] = (float)(1.25 * la[1] / ((double)NR * DZ));
    if (i == 2) out[2] = (float)(1.25 * la[2] / ((double)NR * DZ));
    if (i == 3) out[3] = (float)(1.25 * la[3] / ((double)NR * DZ));
}

// ---------------- launch ----------------

extern "C" void kernel_launch(void* const* d_in, const int* in_sizes, int n_in,
                              void* d_out, int out_size, void* d_ws, size_t ws_size,
                              hipStream_t stream) {
    (void)in_sizes; (void)n_in; (void)out_size; (void)ws_size;
    const float* x   = (const float*)d_in[0];
    const float* ew1 = (const float*)d_in[1];
    const float* eb1 = (const float*)d_in[2];
    const float* ew2 = (const float*)d_in[3];
    const float* eb2 = (const float*)d_in[4];
    const float* dw1 = (const float*)d_in[5];
    const float* db1 = (const float*)d_in[6];
    const float* dw2 = (const float*)d_in[7];
    const float* db2 = (const float*)d_in[8];
    const float* cb0 = (const float*)d_in[9];
    const float* cb1 = (const float*)d_in[10];
    const float* cb2 = (const float*)d_in[11];

    // workspace (~139 MB): lossAcc | R1 67MB: h1 -> h2 | R2 33.5MB: z (bf16) |
    //   R3 33.5MB: zqb | weights bf16 | cbb swizzled | cnorm
    char* ws = (char*)d_ws;
    double* lossAcc = (double*)ws;
    size_t off = 256;
    bf16* h1 = (bf16*)(ws + off);      // R1: h1 (enc), then h2 (dec) after h1 dead
    bf16* h2 = h1;
    off += (size_t)NR * DH * 2;
    bf16* zb = (bf16*)(ws + off);      // R2: z as bf16
    off += (size_t)NR * DZ * 2;
    bf16* zqb = (bf16*)(ws + off);     // R3
    off += (size_t)NR * DZ * 2;
    bf16* w1T = (bf16*)(ws + off); off += (size_t)DH * DIN * 2;
    bf16* w2T = (bf16*)(ws + off); off += (size_t)DZ * DH * 2;
    bf16* w3T = (bf16*)(ws + off); off += (size_t)DH * DZ * 2;
    bf16* w4T = (bf16*)(ws + off); off += (size_t)DIN * DH * 2;
    bf16* cbb = (bf16*)(ws + off); off += (size_t)1792 * DZ * 2;
    float* cnorm = (float*)(ws + off); off += 1792 * 4;

    k_zero<<<1, 64, 0, stream>>>(lossAcc);
    k_wt<<<dim3(DIN / 64, DH / 64), 256, 0, stream>>>(ew1, w1T, DIN, DH);
    k_wt<<<dim3(DH / 64, DZ / 64), 256, 0, stream>>>(ew2, w2T, DH, DZ);
    k_wt<<<dim3(DZ / 64, DH / 64), 256, 0, stream>>>(dw1, w3T, DZ, DH);
    k_wt<<<dim3(DH / 64, DIN / 64), 256, 0, stream>>>(dw2, w4T, DH, DIN);
    k_cb<<<1024, 256, 0, stream>>>(cb0, cbb, cnorm);
    k_cb<<<512, 256, 0, stream>>>(cb1, cbb + (size_t)1024 * DZ, cnorm + 1024);
    k_cb<<<256, 256, 0, stream>>>(cb2, cbb + (size_t)1536 * DZ, cnorm + 1536);

    // encoder: x(f32, staged direct) -> h1 -> z(bf16)
    k_gemm<0, 1, 2><<<(DH / 128) * (NR / 128), 256, 0, stream>>>(
        x, w1T, eb1, h1, nullptr, nullptr, NR, DH, DIN);
    k_gemm<1, 0, 1><<<(DZ / 128) * (NR / 128), 256, 0, stream>>>(
        h1, w2T, eb2, zb, nullptr, nullptr, NR, DZ, DH);

    // residual quantizer (mega-tile LDS staging, 2 sets/wave)
    k_rq<<<NR / 128, 256, 0, stream>>>(zb, cbb, cnorm, cb0, cb1, cb2, zqb, lossAcc);

    // decoder: zq -> h2 (reuses R1) -> MSE vs x
    k_gemm<0, 0, 2><<<(DH / 128) * (NR / 128), 256, 0, stream>>>(
        zqb, w3T, db1, h2, nullptr, nullptr, NR, DH, DZ);
    k_gemm<2, 0, 3><<<(DIN / 128) * (NR / 128), 256, 0, stream>>>(
        h2, w4T, db2, nullptr, x, lossAcc, NR, DIN, DH);

    k_fin<<<1, 64, 0, stream>>>(lossAcc, (float*)d_out);
}

// Round 13
// 681.503 us; speedup vs baseline: 1.6228x; 1.0280x over previous
//
#include <hip/hip_runtime.h>
#include <hip/hip_bf16.h>

typedef __hip_bfloat16 bf16;
typedef __attribute__((ext_vector_type(8))) short bf16x8;
typedef __attribute__((ext_vector_type(4))) float f32x4;

#define NR 65536
#define DIN 1024
#define DH 512
#define DZ 256

__device__ __forceinline__ short f2b(float f) {
    union { __hip_bfloat16 h; short s; } u;
    u.h = __float2bfloat16(f);
    return u.s;
}
__device__ __forceinline__ float b2f(short s) {
    union { short s; __hip_bfloat16 h; } u;
    u.s = s;
    return __bfloat162float(u.h);
}

__device__ __forceinline__ void gll16(const void* g, void* l) {
    __builtin_amdgcn_global_load_lds(
        (const __attribute__((address_space(1))) char*)g,
        (__attribute__((address_space(3))) char*)l, 16, 0, 0);
}

// ---------------- prep kernels ----------------

__global__ void k_zero(double* __restrict__ p) {
    if (threadIdx.x < 4) p[threadIdx.x] = 0.0;
}

// x f32 -> bf16, vectorized grid-stride (8 elems/thread/iter)
__global__ __launch_bounds__(256)
void k_prep_x(const float* __restrict__ x, bf16* __restrict__ xb) {
    const size_t stride = (size_t)gridDim.x * 256 * 8;
    for (size_t i = ((size_t)blockIdx.x * 256 + threadIdx.x) * 8;
         i < (size_t)NR * DIN; i += stride) {
        f32x4 a = *(const f32x4*)(x + i);
        f32x4 b = *(const f32x4*)(x + i + 4);
        bf16x8 o;
        o[0]=f2b(a[0]); o[1]=f2b(a[1]); o[2]=f2b(a[2]); o[3]=f2b(a[3]);
        o[4]=f2b(b[0]); o[5]=f2b(b[1]); o[6]=f2b(b[2]); o[7]=f2b(b[3]);
        *(bf16x8*)((short*)xb + i) = o;
    }
}

// tiled transpose: w[K][N] f32 -> wT[N][K] bf16
__global__ __launch_bounds__(256)
void k_wt(const float* __restrict__ w, bf16* __restrict__ wT, int K, int N) {
    __shared__ float t[64][65];
    const int k0 = blockIdx.x * 64, n0 = blockIdx.y * 64;
    const int tx = threadIdx.x & 63, ty = threadIdx.x >> 6;
    #pragma unroll
    for (int i = 0; i < 16; i++) {
        int r = ty + i * 4;
        t[r][tx] = w[(size_t)(k0 + r) * N + n0 + tx];
    }
    __syncthreads();
    #pragma unroll
    for (int i = 0; i < 16; i++) {
        int r = ty + i * 4;
        wT[(size_t)(n0 + r) * K + k0 + tx] = __float2bfloat16(t[tx][r]);
    }
}

// codebook f32 -> bf16 SWIZZLED copy + squared norms (swizzle matches k_rq reads)
__global__ void k_cb(const float* __restrict__ cb, bf16* __restrict__ cbb,
                     float* __restrict__ cnorm) {
    int cw = blockIdx.x, d = threadIdx.x;
    int dsrc = d ^ ((cw & 7) << 3);
    float v = cb[(size_t)cw * DZ + dsrc];
    cbb[(size_t)cw * DZ + d] = __float2bfloat16(v);
    float s = v * v;
    #pragma unroll
    for (int m = 1; m < 64; m <<= 1) s += __shfl_xor(s, m, 64);
    __shared__ float red[4];
    if ((d & 63) == 0) red[d >> 6] = s;
    __syncthreads();
    if (d == 0) cnorm[cw] = red[0] + red[1] + red[2] + red[3];
}

// ---------------- GEMM: C = epi(A[M,K] @ BT[N,K]^T + bias) ----------------
// All-bf16 path. 1-D grid with XCD-chunked swizzle.
// EPI 0: bias + exact GELU -> bf16 | EPI 1: bias -> bf16 | EPI 2: MSE vs xref(bf16)

template <int EPI, int LOGG>
__global__ __launch_bounds__(256)
void k_gemm(const bf16* __restrict__ A, const bf16* __restrict__ BT,
            const float* __restrict__ bias, bf16* __restrict__ outb,
            const bf16* __restrict__ xref, double* __restrict__ lossAcc,
            int M, int N, int K) {
    __shared__ __align__(16) char AsBuf[8192];
    __shared__ __align__(16) char BsBuf[8192];
    const int tid = threadIdx.x;
    const int bid = blockIdx.x;
    const int tt = bid >> 3;
    const int bn = tt & ((1 << LOGG) - 1);
    const int bm = (bid & 7) + ((tt >> LOGG) << 3);
    const int w = tid >> 6, l = tid & 63, g = l >> 4, c = l & 15;
    const int wr = w >> 1, wc = w & 1;

    f32x4 acc[4][4] = {};

    const int o1 = tid * 16;
    const int o2 = o1 + 4096;
    const int br1 = o1 >> 6, bcol1 = (o1 & 63) >> 1;
    const int br2 = o2 >> 6, bcol2 = (o2 & 63) >> 1;
    const bf16* Abase = A + (size_t)(bm * 128) * K;
    const bf16* Bbase = BT + (size_t)(bn * 128) * K;

    for (int k0 = 0; k0 < K; k0 += 32) {
        __syncthreads();
        gll16(Abase + (size_t)br1 * K + k0 + bcol1, AsBuf + o1);
        gll16(Abase + (size_t)br2 * K + k0 + bcol2, AsBuf + o2);
        gll16(Bbase + (size_t)br1 * K + k0 + bcol1, BsBuf + o1);
        gll16(Bbase + (size_t)br2 * K + k0 + bcol2, BsBuf + o2);
        __syncthreads();

        bf16x8 af[4], bfr[4];
        #pragma unroll
        for (int m = 0; m < 4; m++)
            af[m] = *(const bf16x8*)((const bf16*)AsBuf + (wr * 64 + m * 16 + c) * 32 + g * 8);
        #pragma unroll
        for (int n = 0; n < 4; n++)
            bfr[n] = *(const bf16x8*)((const bf16*)BsBuf + (wc * 64 + n * 16 + c) * 32 + g * 8);
        #pragma unroll
        for (int m = 0; m < 4; m++)
            #pragma unroll
            for (int n = 0; n < 4; n++)
                acc[m][n] = __builtin_amdgcn_mfma_f32_16x16x32_bf16(
                    af[m], bfr[n], acc[m][n], 0, 0, 0);
    }

    float msum = 0.f;
    #pragma unroll
    for (int n = 0; n < 4; n++) {
        const int col = bn * 128 + wc * 64 + n * 16 + c;
        const float bv = bias[col];
        #pragma unroll
        for (int m = 0; m < 4; m++) {
            const int row0 = bm * 128 + wr * 64 + m * 16 + g * 4;
            #pragma unroll
            for (int r = 0; r < 4; r++) {
                float v = acc[m][n][r] + bv;
                int row = row0 + r;
                if (EPI == 0) {
                    float ge = 0.5f * v * (1.f + erff(v * 0.70710678118654752f));
                    outb[(size_t)row * N + col] = __float2bfloat16(ge);
                } else if (EPI == 1) {
                    outb[(size_t)row * N + col] = __float2bfloat16(v);
                } else {
                    float d = v - __bfloat162float(xref[(size_t)row * N + col]);
                    msum += d * d;
                }
            }
        }
    }
    if (EPI == 2) {
        #pragma unroll
        for (int m = 1; m < 64; m <<= 1) msum += __shfl_xor(msum, m, 64);
        if (l == 0) atomicAdd(lossAcc, (double)msum);
    }
}

// ---------------- fused residual quantizer v3 (unchanged from r12) --------
// zqb may alias z (in-place): each thread reads then writes only its own rows.

__global__ __launch_bounds__(256)
void k_rq(const bf16* __restrict__ z, const bf16* __restrict__ cbb,
          const float* __restrict__ cnorm,
          const float* __restrict__ cbf0, const float* __restrict__ cbf1,
          const float* __restrict__ cbf2,
          bf16* __restrict__ zqb, double* __restrict__ lossAcc) {
    __shared__ __align__(16) char mt[65536];
    __shared__ float cn_lds[1792];
    const int tid = threadIdx.x;
    const int w = tid >> 6, l = tid & 63, g = l >> 4, c = l & 15;
    const int rowbase = blockIdx.x * 128 + w * 32;

    for (int i = tid; i < 1792; i += 256) cn_lds[i] = cnorm[i];

    bf16x8 af[2][8];
    #pragma unroll
    for (int m = 0; m < 2; m++) {
        const short* zp = (const short*)z + (size_t)(rowbase + m * 16 + c) * DZ + g * 8;
        #pragma unroll
        for (int kk = 0; kk < 8; kk++)
            af[m][kk] = *(const bf16x8*)(zp + kk * 32);
    }

    const int c0 = c & 7;
    const int Pbase = c * 512 + ((g * 16) ^ ((c0 & 3) << 4)) + ((c0 >> 2) << 6);

    const float* cbf[3] = {cbf0, cbf1, cbf2};
    const int Ks[3] = {1024, 512, 256};
    int mtg = 0, cnbase = 0;
    float lsum[3];

    for (int s = 0; s < 3; s++) {
        const int nmt = Ks[s] >> 7;
        float minv[2][4] = {{3.4e38f, 3.4e38f, 3.4e38f, 3.4e38f},
                            {3.4e38f, 3.4e38f, 3.4e38f, 3.4e38f}};
        int mini[2][4] = {};
        for (int imt = 0; imt < nmt; imt++, mtg++) {
            __syncthreads();
            const char* src = (const char*)cbb + (size_t)mtg * 65536 + tid * 16;
            #pragma unroll
            for (int st = 0; st < 16; st++)
                gll16(src + (size_t)st * 4096, mt + st * 4096 + tid * 16);
            __syncthreads();
            #pragma unroll
            for (int sub = 0; sub < 8; sub++) {
                const char* tp = mt + sub * 8192;
                bf16x8 bfr[8];
                #pragma unroll
                for (int kk = 0; kk < 8; kk++)
                    bfr[kk] = *(const bf16x8*)(tp + (Pbase ^ (kk << 6)));
                f32x4 a0 = {0.f, 0.f, 0.f, 0.f}, a1 = {0.f, 0.f, 0.f, 0.f};
                #pragma unroll
                for (int kk = 0; kk < 8; kk++) {
                    a0 = __builtin_amdgcn_mfma_f32_16x16x32_bf16(af[0][kk], bfr[kk], a0, 0, 0, 0);
                    a1 = __builtin_amdgcn_mfma_f32_16x16x32_bf16(af[1][kk], bfr[kk], a1, 0, 0, 0);
                }
                const int cw = imt * 128 + sub * 16 + c;
                const float cn = cn_lds[cnbase + cw];
                #pragma unroll
                for (int r = 0; r < 4; r++) {
                    float d0 = cn - 2.0f * a0[r];
                    if (d0 < minv[0][r]) { minv[0][r] = d0; mini[0][r] = cw; }
                    float d1 = cn - 2.0f * a1[r];
                    if (d1 < minv[1][r]) { minv[1][r] = d1; mini[1][r] = cw; }
                }
            }
        }
        float ls = 0.f;
        #pragma unroll
        for (int m = 0; m < 2; m++) {
            #pragma unroll
            for (int mm = 1; mm < 16; mm <<= 1) {
                #pragma unroll
                for (int r = 0; r < 4; r++) {
                    float ov = __shfl_xor(minv[m][r], mm, 64);
                    int   oi = __shfl_xor(mini[m][r], mm, 64);
                    if (ov < minv[m][r] || (ov == minv[m][r] && oi < mini[m][r])) {
                        minv[m][r] = ov; mini[m][r] = oi;
                    }
                }
            }
            int srcl = (c >> 2) << 4;
            int i0 = __shfl(mini[m][0], srcl, 64);
            int i1 = __shfl(mini[m][1], srcl, 64);
            int i2 = __shfl(mini[m][2], srcl, 64);
            int i3 = __shfl(mini[m][3], srcl, 64);
            int rr = c & 3;
            int myidx = rr == 0 ? i0 : rr == 1 ? i1 : rr == 2 ? i2 : i3;

            const float* qp = cbf[s] + (size_t)myidx * DZ + g * 8;
            #pragma unroll
            for (int kk = 0; kk < 8; kk++) {
                f32x4 q0 = *(const f32x4*)(qp + kk * 32);
                f32x4 q1 = *(const f32x4*)(qp + kk * 32 + 4);
                bf16x8 a = af[m][kk];
                bf16x8 t;
                #pragma unroll
                for (int j = 0; j < 4; j++) {
                    float d = b2f(a[j]) - q0[j];
                    ls += d * d; t[j] = f2b(d);
                }
                #pragma unroll
                for (int j = 0; j < 4; j++) {
                    float d = b2f(a[4 + j]) - q1[j];
                    ls += d * d; t[4 + j] = f2b(d);
                }
                af[m][kk] = t;
            }
        }
        lsum[s] = ls;
        cnbase += Ks[s];
    }

    // zq = z - res_final (in-place safe: same thread, read-then-write per elem)
    #pragma unroll
    for (int m = 0; m < 2; m++) {
        const short* zp = (const short*)z + (size_t)(rowbase + m * 16 + c) * DZ + g * 8;
        short* op = (short*)zqb + (size_t)(rowbase + m * 16 + c) * DZ + g * 8;
        #pragma unroll
        for (int kk = 0; kk < 8; kk++) {
            bf16x8 zv = *(const bf16x8*)(zp + kk * 32);
            bf16x8 a = af[m][kk];
            bf16x8 o;
            #pragma unroll
            for (int j = 0; j < 8; j++)
                o[j] = f2b(b2f(zv[j]) - b2f(a[j]));
            *(bf16x8*)(op + kk * 32) = o;
        }
    }

    #pragma unroll
    for (int s = 0; s < 3; s++) {
        float v = lsum[s];
        #pragma unroll
        for (int mm = 1; mm < 64; mm <<= 1) v += __shfl_xor(v, mm, 64);
        if (l == 0) atomicAdd(&lossAcc[1 + s], (double)v);
    }
}

// ---------------- final: output float32 (4 scalars) ----------------

__global__ void k_fin(const double* __restrict__ la, float* __restrict__ out) {
    int i = threadIdx.x;
    if (i == 0) out[0] = (float)(la[0] / ((double)NR * DIN));
    if (i == 1) out[1] = (float)(1.25 * la[1] / ((double)NR * DZ));
    if (i == 2) out[2] = (float)(1.25 * la[2] / ((double)NR * DZ));
    if (i == 3) out[3] = (float)(1.25 * la[3] / ((double)NR * DZ));
}

// ---------------- launch ----------------

extern "C" void kernel_launch(void* const* d_in, const int* in_sizes, int n_in,
                              void* d_out, int out_size, void* d_ws, size_t ws_size,
                              hipStream_t stream) {
    (void)in_sizes; (void)n_in; (void)out_size; (void)ws_size;
    const float* x   = (const float*)d_in[0];
    const float* ew1 = (const float*)d_in[1];
    const float* eb1 = (const float*)d_in[2];
    const float* ew2 = (const float*)d_in[3];
    const float* eb2 = (const float*)d_in[4];
    const float* dw1 = (const float*)d_in[5];
    const float* db1 = (const float*)d_in[6];
    const float* dw2 = (const float*)d_in[7];
    const float* db2 = (const float*)d_in[8];
    const float* cb0 = (const float*)d_in[9];
    const float* cb1 = (const float*)d_in[10];
    const float* cb2 = (const float*)d_in[11];

    // workspace (~236 MB): lossAcc | xb 134MB | R1 67MB: h1->h2 | zb 33.5MB (zq in-place)
    //   | weights bf16 | cbb swizzled | cnorm
    char* ws = (char*)d_ws;
    double* lossAcc = (double*)ws;
    size_t off = 256;
    bf16* xb = (bf16*)(ws + off);
    off += (size_t)NR * DIN * 2;
    bf16* h1 = (bf16*)(ws + off);      // h1 (enc), then h2 (dec) after h1 dead
    bf16* h2 = h1;
    off += (size_t)NR * DH * 2;
    bf16* zb = (bf16*)(ws + off);      // z, overwritten with zq in-place by k_rq
    off += (size_t)NR * DZ * 2;
    bf16* w1T = (bf16*)(ws + off); off += (size_t)DH * DIN * 2;
    bf16* w2T = (bf16*)(ws + off); off += (size_t)DZ * DH * 2;
    bf16* w3T = (bf16*)(ws + off); off += (size_t)DH * DZ * 2;
    bf16* w4T = (bf16*)(ws + off); off += (size_t)DIN * DH * 2;
    bf16* cbb = (bf16*)(ws + off); off += (size_t)1792 * DZ * 2;
    float* cnorm = (float*)(ws + off); off += 1792 * 4;

    k_zero<<<1, 64, 0, stream>>>(lossAcc);
    k_prep_x<<<4096, 256, 0, stream>>>(x, xb);
    k_wt<<<dim3(DIN / 64, DH / 64), 256, 0, stream>>>(ew1, w1T, DIN, DH);
    k_wt<<<dim3(DH / 64, DZ / 64), 256, 0, stream>>>(ew2, w2T, DH, DZ);
    k_wt<<<dim3(DZ / 64, DH / 64), 256, 0, stream>>>(dw1, w3T, DZ, DH);
    k_wt<<<dim3(DH / 64, DIN / 64), 256, 0, stream>>>(dw2, w4T, DH, DIN);
    k_cb<<<1024, 256, 0, stream>>>(cb0, cbb, cnorm);
    k_cb<<<512, 256, 0, stream>>>(cb1, cbb + (size_t)1024 * DZ, cnorm + 1024);
    k_cb<<<256, 256, 0, stream>>>(cb2, cbb + (size_t)1536 * DZ, cnorm + 1536);

    // encoder: xb -> h1 -> zb
    k_gemm<0, 2><<<(DH / 128) * (NR / 128), 256, 0, stream>>>(
        xb, w1T, eb1, h1, nullptr, nullptr, NR, DH, DIN);
    k_gemm<1, 1><<<(DZ / 128) * (NR / 128), 256, 0, stream>>>(
        h1, w2T, eb2, zb, nullptr, nullptr, NR, DZ, DH);

    // residual quantizer (zq overwrites zb in place)
    k_rq<<<NR / 128, 256, 0, stream>>>(zb, cbb, cnorm, cb0, cb1, cb2, zb, lossAcc);

    // decoder: zq -> h2 -> MSE vs xb (bf16)
    k_gemm<0, 2><<<(DH / 128) * (NR / 128), 256, 0, stream>>>(
        zb, w3T, db1, h2, nullptr, nullptr, NR, DH, DZ);
    k_gemm<2, 3><<<(DIN / 128) * (NR / 128), 256, 0, stream>>>(
        h2, w4T, db2, nullptr, xb, lossAcc, NR, DIN, DH);

    k_fin<<<1, 64, 0, stream>>>(lossAcc, (float*)d_out);
}

// Round 14
// 677.307 us; speedup vs baseline: 1.6328x; 1.0062x over previous
//
#include <hip/hip_runtime.h>
#include <hip/hip_bf16.h>

typedef __hip_bfloat16 bf16;
typedef __attribute__((ext_vector_type(8))) short bf16x8;
typedef __attribute__((ext_vector_type(4))) float f32x4;

#define NR 65536
#define DIN 1024
#define DH 512
#define DZ 256

__device__ __forceinline__ short f2b(float f) {
    union { __hip_bfloat16 h; short s; } u;
    u.h = __float2bfloat16(f);
    return u.s;
}
__device__ __forceinline__ float b2f(short s) {
    union { short s; __hip_bfloat16 h; } u;
    u.s = s;
    return __bfloat162float(u.h);
}

__device__ __forceinline__ void gll16(const void* g, void* l) {
    __builtin_amdgcn_global_load_lds(
        (const __attribute__((address_space(1))) char*)g,
        (__attribute__((address_space(3))) char*)l, 16, 0, 0);
}

// ---------------- prep kernels ----------------

__global__ void k_zero(double* __restrict__ p) {
    if (threadIdx.x < 4) p[threadIdx.x] = 0.0;
}

// x f32 -> bf16, vectorized grid-stride
__global__ __launch_bounds__(256)
void k_prep_x(const float* __restrict__ x, bf16* __restrict__ xb) {
    const size_t stride = (size_t)gridDim.x * 256 * 8;
    for (size_t i = ((size_t)blockIdx.x * 256 + threadIdx.x) * 8;
         i < (size_t)NR * DIN; i += stride) {
        f32x4 a = *(const f32x4*)(x + i);
        f32x4 b = *(const f32x4*)(x + i + 4);
        bf16x8 o;
        o[0]=f2b(a[0]); o[1]=f2b(a[1]); o[2]=f2b(a[2]); o[3]=f2b(a[3]);
        o[4]=f2b(b[0]); o[5]=f2b(b[1]); o[6]=f2b(b[2]); o[7]=f2b(b[3]);
        *(bf16x8*)((short*)xb + i) = o;
    }
}

// tiled transpose: w[K][N] f32 -> wT[N][K] bf16
__global__ __launch_bounds__(256)
void k_wt(const float* __restrict__ w, bf16* __restrict__ wT, int K, int N) {
    __shared__ float t[64][65];
    const int k0 = blockIdx.x * 64, n0 = blockIdx.y * 64;
    const int tx = threadIdx.x & 63, ty = threadIdx.x >> 6;
    #pragma unroll
    for (int i = 0; i < 16; i++) {
        int r = ty + i * 4;
        t[r][tx] = w[(size_t)(k0 + r) * N + n0 + tx];
    }
    __syncthreads();
    #pragma unroll
    for (int i = 0; i < 16; i++) {
        int r = ty + i * 4;
        wT[(size_t)(n0 + r) * K + k0 + tx] = __float2bfloat16(t[tx][r]);
    }
}

// codebook f32 -> bf16 SWIZZLED copy + squared norms (swizzle matches k_rq reads)
__global__ void k_cb(const float* __restrict__ cb, bf16* __restrict__ cbb,
                     float* __restrict__ cnorm) {
    int cw = blockIdx.x, d = threadIdx.x;
    int dsrc = d ^ ((cw & 7) << 3);
    float v = cb[(size_t)cw * DZ + dsrc];
    cbb[(size_t)cw * DZ + d] = __float2bfloat16(v);
    float s = v * v;
    #pragma unroll
    for (int m = 1; m < 64; m <<= 1) s += __shfl_xor(s, m, 64);
    __shared__ float red[4];
    if ((d & 63) == 0) red[d >> 6] = s;
    __syncthreads();
    if (d == 0) cnorm[cw] = red[0] + red[1] + red[2] + red[3];
}

// ---------------- GEMM v2: BK=64 + XOR-swizzled LDS ----------------
// C = epi(A[M,K] @ BT[N,K]^T + bias); 1-D grid with XCD-chunked swizzle.
// LDS tiles [128 rows][64 cols] bf16 = 128B/row; 16B-slot index XORed with
// (row&7) on BOTH the global source (staging) and the ds_read (fragments) —
// LDS dest stays linear for global_load_lds (rule #21).
// EPI 0: bias + exact GELU -> bf16 | EPI 1: bias -> bf16 | EPI 2: MSE vs xref

template <int EPI, int LOGG>
__global__ __launch_bounds__(256)
void k_gemm(const bf16* __restrict__ A, const bf16* __restrict__ BT,
            const float* __restrict__ bias, bf16* __restrict__ outb,
            const bf16* __restrict__ xref, double* __restrict__ lossAcc,
            int M, int N, int K) {
    __shared__ __align__(16) char AsBuf[16384];
    __shared__ __align__(16) char BsBuf[16384];
    const int tid = threadIdx.x;
    const int bid = blockIdx.x;
    const int tt = bid >> 3;
    const int bn = tt & ((1 << LOGG) - 1);
    const int bm = (bid & 7) + ((tt >> LOGG) << 3);
    const int w = tid >> 6, l = tid & 63, g = l >> 4, c = l & 15;
    const int wr = w >> 1, wc = w & 1;

    f32x4 acc[4][4] = {};

    // staging geometry: 4 chunks x 4KB; chunk j at ob = tid*16 + j*4096
    // row = ob>>7, slot = (ob&127)>>4, swizzled source slot = slot ^ (row&7)
    const int o1 = tid * 16;
    int srow[4], scol[4];
    #pragma unroll
    for (int j = 0; j < 4; j++) {
        const int ob = o1 + j * 4096;
        srow[j] = ob >> 7;
        scol[j] = (((ob & 127) >> 4) ^ (srow[j] & 7)) << 3;   // bf16 elems
    }
    const bf16* Abase = A + (size_t)(bm * 128) * K;
    const bf16* Bbase = BT + (size_t)(bn * 128) * K;

    for (int k0 = 0; k0 < K; k0 += 64) {
        __syncthreads();
        #pragma unroll
        for (int j = 0; j < 4; j++)
            gll16(Abase + (size_t)srow[j] * K + k0 + scol[j], AsBuf + o1 + j * 4096);
        #pragma unroll
        for (int j = 0; j < 4; j++)
            gll16(Bbase + (size_t)srow[j] * K + k0 + scol[j], BsBuf + o1 + j * 4096);
        __syncthreads();

        #pragma unroll
        for (int h = 0; h < 2; h++) {
            bf16x8 af[4], bfr[4];
            #pragma unroll
            for (int m = 0; m < 4; m++) {
                const int rr = wr * 64 + m * 16 + c;
                af[m] = *(const bf16x8*)(AsBuf + rr * 128 + (((h << 2) + g) ^ (rr & 7)) * 16);
            }
            #pragma unroll
            for (int n = 0; n < 4; n++) {
                const int rr = wc * 64 + n * 16 + c;
                bfr[n] = *(const bf16x8*)(BsBuf + rr * 128 + (((h << 2) + g) ^ (rr & 7)) * 16);
            }
            #pragma unroll
            for (int m = 0; m < 4; m++)
                #pragma unroll
                for (int n = 0; n < 4; n++)
                    acc[m][n] = __builtin_amdgcn_mfma_f32_16x16x32_bf16(
                        af[m], bfr[n], acc[m][n], 0, 0, 0);
        }
    }

    float msum = 0.f;
    #pragma unroll
    for (int n = 0; n < 4; n++) {
        const int col = bn * 128 + wc * 64 + n * 16 + c;
        const float bv = bias[col];
        #pragma unroll
        for (int m = 0; m < 4; m++) {
            const int row0 = bm * 128 + wr * 64 + m * 16 + g * 4;
            #pragma unroll
            for (int r = 0; r < 4; r++) {
                float v = acc[m][n][r] + bv;
                int row = row0 + r;
                if (EPI == 0) {
                    float ge = 0.5f * v * (1.f + erff(v * 0.70710678118654752f));
                    outb[(size_t)row * N + col] = __float2bfloat16(ge);
                } else if (EPI == 1) {
                    outb[(size_t)row * N + col] = __float2bfloat16(v);
                } else {
                    float d = v - __bfloat162float(xref[(size_t)row * N + col]);
                    msum += d * d;
                }
            }
        }
    }
    if (EPI == 2) {
        #pragma unroll
        for (int m = 1; m < 64; m <<= 1) msum += __shfl_xor(msum, m, 64);
        if (l == 0) atomicAdd(lossAcc, (double)msum);
    }
}

// ---------------- fused residual quantizer v3 (unchanged from r13) --------

__global__ __launch_bounds__(256)
void k_rq(const bf16* __restrict__ z, const bf16* __restrict__ cbb,
          const float* __restrict__ cnorm,
          const float* __restrict__ cbf0, const float* __restrict__ cbf1,
          const float* __restrict__ cbf2,
          bf16* __restrict__ zqb, double* __restrict__ lossAcc) {
    __shared__ __align__(16) char mt[65536];
    __shared__ float cn_lds[1792];
    const int tid = threadIdx.x;
    const int w = tid >> 6, l = tid & 63, g = l >> 4, c = l & 15;
    const int rowbase = blockIdx.x * 128 + w * 32;

    for (int i = tid; i < 1792; i += 256) cn_lds[i] = cnorm[i];

    bf16x8 af[2][8];
    #pragma unroll
    for (int m = 0; m < 2; m++) {
        const short* zp = (const short*)z + (size_t)(rowbase + m * 16 + c) * DZ + g * 8;
        #pragma unroll
        for (int kk = 0; kk < 8; kk++)
            af[m][kk] = *(const bf16x8*)(zp + kk * 32);
    }

    const int c0 = c & 7;
    const int Pbase = c * 512 + ((g * 16) ^ ((c0 & 3) << 4)) + ((c0 >> 2) << 6);

    const float* cbf[3] = {cbf0, cbf1, cbf2};
    const int Ks[3] = {1024, 512, 256};
    int mtg = 0, cnbase = 0;
    float lsum[3];

    for (int s = 0; s < 3; s++) {
        const int nmt = Ks[s] >> 7;
        float minv[2][4] = {{3.4e38f, 3.4e38f, 3.4e38f, 3.4e38f},
                            {3.4e38f, 3.4e38f, 3.4e38f, 3.4e38f}};
        int mini[2][4] = {};
        for (int imt = 0; imt < nmt; imt++, mtg++) {
            __syncthreads();
            const char* src = (const char*)cbb + (size_t)mtg * 65536 + tid * 16;
            #pragma unroll
            for (int st = 0; st < 16; st++)
                gll16(src + (size_t)st * 4096, mt + st * 4096 + tid * 16);
            __syncthreads();
            #pragma unroll
            for (int sub = 0; sub < 8; sub++) {
                const char* tp = mt + sub * 8192;
                bf16x8 bfr[8];
                #pragma unroll
                for (int kk = 0; kk < 8; kk++)
                    bfr[kk] = *(const bf16x8*)(tp + (Pbase ^ (kk << 6)));
                f32x4 a0 = {0.f, 0.f, 0.f, 0.f}, a1 = {0.f, 0.f, 0.f, 0.f};
                #pragma unroll
                for (int kk = 0; kk < 8; kk++) {
                    a0 = __builtin_amdgcn_mfma_f32_16x16x32_bf16(af[0][kk], bfr[kk], a0, 0, 0, 0);
                    a1 = __builtin_amdgcn_mfma_f32_16x16x32_bf16(af[1][kk], bfr[kk], a1, 0, 0, 0);
                }
                const int cw = imt * 128 + sub * 16 + c;
                const float cn = cn_lds[cnbase + cw];
                #pragma unroll
                for (int r = 0; r < 4; r++) {
                    float d0 = cn - 2.0f * a0[r];
                    if (d0 < minv[0][r]) { minv[0][r] = d0; mini[0][r] = cw; }
                    float d1 = cn - 2.0f * a1[r];
                    if (d1 < minv[1][r]) { minv[1][r] = d1; mini[1][r] = cw; }
                }
            }
        }
        float ls = 0.f;
        #pragma unroll
        for (int m = 0; m < 2; m++) {
            #pragma unroll
            for (int mm = 1; mm < 16; mm <<= 1) {
                #pragma unroll
                for (int r = 0; r < 4; r++) {
                    float ov = __shfl_xor(minv[m][r], mm, 64);
                    int   oi = __shfl_xor(mini[m][r], mm, 64);
                    if (ov < minv[m][r] || (ov == minv[m][r] && oi < mini[m][r])) {
                        minv[m][r] = ov; mini[m][r] = oi;
                    }
                }
            }
            int srcl = (c >> 2) << 4;
            int i0 = __shfl(mini[m][0], srcl, 64);
            int i1 = __shfl(mini[m][1], srcl, 64);
            int i2 = __shfl(mini[m][2], srcl, 64);
            int i3 = __shfl(mini[m][3], srcl, 64);
            int rr = c & 3;
            int myidx = rr == 0 ? i0 : rr == 1 ? i1 : rr == 2 ? i2 : i3;

            const float* qp = cbf[s] + (size_t)myidx * DZ + g * 8;
            #pragma unroll
            for (int kk = 0; kk < 8; kk++) {
                f32x4 q0 = *(const f32x4*)(qp + kk * 32);
                f32x4 q1 = *(const f32x4*)(qp + kk * 32 + 4);
                bf16x8 a = af[m][kk];
                bf16x8 t;
                #pragma unroll
                for (int j = 0; j < 4; j++) {
                    float d = b2f(a[j]) - q0[j];
                    ls += d * d; t[j] = f2b(d);
                }
                #pragma unroll
                for (int j = 0; j < 4; j++) {
                    float d = b2f(a[4 + j]) - q1[j];
                    ls += d * d; t[4 + j] = f2b(d);
                }
                af[m][kk] = t;
            }
        }
        lsum[s] = ls;
        cnbase += Ks[s];
    }

    #pragma unroll
    for (int m = 0; m < 2; m++) {
        const short* zp = (const short*)z + (size_t)(rowbase + m * 16 + c) * DZ + g * 8;
        short* op = (short*)zqb + (size_t)(rowbase + m * 16 + c) * DZ + g * 8;
        #pragma unroll
        for (int kk = 0; kk < 8; kk++) {
            bf16x8 zv = *(const bf16x8*)(zp + kk * 32);
            bf16x8 a = af[m][kk];
            bf16x8 o;
            #pragma unroll
            for (int j = 0; j < 8; j++)
                o[j] = f2b(b2f(zv[j]) - b2f(a[j]));
            *(bf16x8*)(op + kk * 32) = o;
        }
    }

    #pragma unroll
    for (int s = 0; s < 3; s++) {
        float v = lsum[s];
        #pragma unroll
        for (int mm = 1; mm < 64; mm <<= 1) v += __shfl_xor(v, mm, 64);
        if (l == 0) atomicAdd(&lossAcc[1 + s], (double)v);
    }
}

// ---------------- final: output float32 (4 scalars) ----------------

__global__ void k_fin(const double* __restrict__ la, float* __restrict__ out) {
    int i = threadIdx.x;
    if (i == 0) out[0] = (float)(la[0] / ((double)NR * DIN));
    if (i == 1) out[1] = (float)(1.25 * la[1] / ((double)NR * DZ));
    if (i == 2) out[2] = (float)(1.25 * la[2] / ((double)NR * DZ));
    if (i == 3) out[3] = (float)(1.25 * la[3] / ((double)NR * DZ));
}

// ---------------- launch ----------------

extern "C" void kernel_launch(void* const* d_in, const int* in_sizes, int n_in,
                              void* d_out, int out_size, void* d_ws, size_t ws_size,
                              hipStream_t stream) {
    (void)in_sizes; (void)n_in; (void)out_size; (void)ws_size;
    const float* x   = (const float*)d_in[0];
    const float* ew1 = (const float*)d_in[1];
    const float* eb1 = (const float*)d_in[2];
    const float* ew2 = (const float*)d_in[3];
    const float* eb2 = (const float*)d_in[4];
    const float* dw1 = (const float*)d_in[5];
    const float* db1 = (const float*)d_in[6];
    const float* dw2 = (const float*)d_in[7];
    const float* db2 = (const float*)d_in[8];
    const float* cb0 = (const float*)d_in[9];
    const float* cb1 = (const float*)d_in[10];
    const float* cb2 = (const float*)d_in[11];

    // workspace (~236 MB)
    char* ws = (char*)d_ws;
    double* lossAcc = (double*)ws;
    size_t off = 256;
    bf16* xb = (bf16*)(ws + off);
    off += (size_t)NR * DIN * 2;
    bf16* h1 = (bf16*)(ws + off);      // h1 (enc), then h2 (dec) after h1 dead
    bf16* h2 = h1;
    off += (size_t)NR * DH * 2;
    bf16* zb = (bf16*)(ws + off);      // z, overwritten with zq in-place by k_rq
    off += (size_t)NR * DZ * 2;
    bf16* w1T = (bf16*)(ws + off); off += (size_t)DH * DIN * 2;
    bf16* w2T = (bf16*)(ws + off); off += (size_t)DZ * DH * 2;
    bf16* w3T = (bf16*)(ws + off); off += (size_t)DH * DZ * 2;
    bf16* w4T = (bf16*)(ws + off); off += (size_t)DIN * DH * 2;
    bf16* cbb = (bf16*)(ws + off); off += (size_t)1792 * DZ * 2;
    float* cnorm = (float*)(ws + off); off += 1792 * 4;

    k_zero<<<1, 64, 0, stream>>>(lossAcc);
    k_prep_x<<<4096, 256, 0, stream>>>(x, xb);
    k_wt<<<dim3(DIN / 64, DH / 64), 256, 0, stream>>>(ew1, w1T, DIN, DH);
    k_wt<<<dim3(DH / 64, DZ / 64), 256, 0, stream>>>(ew2, w2T, DH, DZ);
    k_wt<<<dim3(DZ / 64, DH / 64), 256, 0, stream>>>(dw1, w3T, DZ, DH);
    k_wt<<<dim3(DH / 64, DIN / 64), 256, 0, stream>>>(dw2, w4T, DH, DIN);
    k_cb<<<1024, 256, 0, stream>>>(cb0, cbb, cnorm);
    k_cb<<<512, 256, 0, stream>>>(cb1, cbb + (size_t)1024 * DZ, cnorm + 1024);
    k_cb<<<256, 256, 0, stream>>>(cb2, cbb + (size_t)1536 * DZ, cnorm + 1536);

    // encoder: xb -> h1 -> zb
    k_gemm<0, 2><<<(DH / 128) * (NR / 128), 256, 0, stream>>>(
        xb, w1T, eb1, h1, nullptr, nullptr, NR, DH, DIN);
    k_gemm<1, 1><<<(DZ / 128) * (NR / 128), 256, 0, stream>>>(
        h1, w2T, eb2, zb, nullptr, nullptr, NR, DZ, DH);

    // residual quantizer (zq overwrites zb in place)
    k_rq<<<NR / 128, 256, 0, stream>>>(zb, cbb, cnorm, cb0, cb1, cb2, zb, lossAcc);

    // decoder: zq -> h2 -> MSE vs xb (bf16)
    k_gemm<0, 2><<<(DH / 128) * (NR / 128), 256, 0, stream>>>(
        zb, w3T, db1, h2, nullptr, nullptr, NR, DH, DZ);
    k_gemm<2, 3><<<(DIN / 128) * (NR / 128), 256, 0, stream>>>(
        h2, w4T, db2, nullptr, xb, lossAcc, NR, DIN, DH);

    k_fin<<<1, 64, 0, stream>>>(lossAcc, (float*)d_out);
}